// Round 5
// baseline (219.829 us; speedup 1.0000x reference)
//
#include <hip/hip_runtime.h>
#include <stdint.h>

#define NGC 4096   // both node counts
#define FIN 512
#define DD  256

typedef __attribute__((ext_vector_type(8))) short short8;
typedef __attribute__((ext_vector_type(4))) float f32x4;
typedef unsigned short u16;
typedef unsigned int   u32;
typedef unsigned long long u64;

static __device__ __forceinline__ float bf2f(u16 u){ return __uint_as_float(((u32)u)<<16); }
static __device__ __forceinline__ u16 f2bf(float f){
  u32 u = __float_as_uint(f);
  u += 0x7fffu + ((u>>16)&1u);
  return (u16)(u>>16);
}
static __device__ __forceinline__ float lk(float x){ return fmaxf(x, 0.2f*x); }
static __device__ __forceinline__ u64 shfl_xor64(u64 x, int m){
  u32 lo = (u32)x, hi = (u32)(x >> 32);
  lo = __shfl_xor(lo, m); hi = __shfl_xor(hi, m);
  return ((u64)hi << 32) | lo;
}

// ---------------------------------------------------------------------------
// k_wcvt: W (f32) -> bf16 copies for the GEMM.
// ---------------------------------------------------------------------------
__global__ __launch_bounds__(256) void k_wcvt(
    const float* __restrict__ Wg, const float* __restrict__ Wc,
    u16* __restrict__ Wgbf, u16* __restrict__ Wcbf)
{
  int base = (blockIdx.x*256 + threadIdx.x)*4;   // grid 128 -> 131072 elems
  float4 a = *(const float4*)(Wg + base);
  float4 b = *(const float4*)(Wc + base);
  ushort4 oa, ob;
  oa.x=f2bf(a.x); oa.y=f2bf(a.y); oa.z=f2bf(a.z); oa.w=f2bf(a.w);
  ob.x=f2bf(b.x); ob.y=f2bf(b.y); ob.z=f2bf(b.z); ob.w=f2bf(b.w);
  *(ushort4*)(Wgbf + base) = oa;
  *(ushort4*)(Wcbf + base) = ob;
}

// ---------------------------------------------------------------------------
// k_pack: bit-pack 3 adjacency matrices (f32 0/1 -> 1 bit), PLAIN layout:
// bit k of row r at u64 word [r*64 + k/64]. One wave per row; float4 loads
// (1KB/wave-instr) + shuffle-tree compaction -> one u64 per lane ->
// single coalesced 512B store per wave.
// ---------------------------------------------------------------------------
__global__ __launch_bounds__(256) void k_pack(
    const float* __restrict__ gene_adj, const float* __restrict__ cell_adj,
    const float* __restrict__ gc_adj,   u64* __restrict__ packbits)
{
  int t = threadIdx.x, wid = t>>6, lane = t&63;
  int gw = blockIdx.x*4 + wid;          // 0..12287
  int mat = gw >> 12;
  int row = gw & 4095;
  const float* src = (mat==0) ? gene_adj : (mat==1) ? cell_adj : gc_adj;
  const float* rp = src + (size_t)row*NGC;

  u64 myword = 0;
  #pragma unroll
  for(int i = 0; i < 16; i++){
    float4 v = *(const float4*)(rp + i*256 + lane*4);
    u32 nib = (v.x!=0.f?1u:0u) | (v.y!=0.f?2u:0u) | (v.z!=0.f?4u:0u) | (v.w!=0.f?8u:0u);
    u32 b  = nib | (__shfl_xor((int)nib, 1) << 4);   // even lanes: byte
    u32 h  = b   | (__shfl_xor((int)b,   2) << 8);   // lanes%4==0: u16
    u32 w  = h   | (__shfl_xor((int)h,   4) << 16);  // lanes%8==0: u32
    u32 o  = (u32)__shfl_xor((int)w, 8);             // lanes%16==0: pair
    u32 flo = w, fhi = o;                            // u64 at lanes 16q: elems [i*256+64q, +64)
    int srcl = ((lane - i*4) << 4) & 63;             // target lanes i*4+q read from lane 16q
    u32 glo = (u32)__shfl((int)flo, srcl);
    u32 ghi = (u32)__shfl((int)fhi, srcl);
    if((lane >> 2) == i) myword = ((u64)ghi << 32) | (u64)glo;
  }
  packbits[((size_t)mat << 18) + (size_t)row*64 + lane] = myword;
}

// ---------------------------------------------------------------------------
// k_bitTT: transpose gc bits -> bitsT (both PLAIN layout, u64 load/store).
// One wave per 64x64-bit tile; 4096 tiles; 4 waves/block -> 1024 blocks.
// ---------------------------------------------------------------------------
__global__ __launch_bounds__(256) void k_bitTT(
    const u64* __restrict__ gcb, u64* __restrict__ bT)
{
  int t = threadIdx.x, wid = t>>6, lane = t&63;
  int id = blockIdx.x*4 + wid;          // 0..4095
  int G = id & 63, C = id >> 6;

  u64 x = gcb[(size_t)(64*G + lane)*64 + C];

  const u64 M1  = 0xAAAAAAAAAAAAAAAAull;
  const u64 M2  = 0xCCCCCCCCCCCCCCCCull;
  const u64 M4  = 0xF0F0F0F0F0F0F0F0ull;
  const u64 M8  = 0xFF00FF00FF00FF00ull;
  const u64 M16 = 0xFFFF0000FFFF0000ull;
  const u64 M32 = 0xFFFFFFFF00000000ull;
  #define TSTEP(S, M) { u64 y = shfl_xor64(x, S); \
    x = (lane & S) ? ((x & (M)) | ((y >> S) & ~(M))) \
                   : ((x & ~(M)) | ((y << S) & (M))); }
  TSTEP(32, M32) TSTEP(16, M16) TSTEP(8, M8)
  TSTEP(4,  M4)  TSTEP(2,  M2)  TSTEP(1, M1)
  #undef TSTEP

  bT[(size_t)(64*C + lane)*64 + G] = x;
}

// ---------------------------------------------------------------------------
// k_hgemm: h = x @ W.T  (f32 x in -> bf16 staged, f32 h out + bf16 hT out)
// grid (64 row-tiles, 2 sides), 512 threads (8 waves). BM=64, BK=64, N=256.
// ---------------------------------------------------------------------------
__global__ __launch_bounds__(512) void k_hgemm(
    const float* __restrict__ xg, const float* __restrict__ xc,
    const u16* __restrict__ Wg, const u16* __restrict__ Wc,
    float* __restrict__ hg, float* __restrict__ hc,
    u16* __restrict__ hTg, u16* __restrict__ hTc)
{
  const int side = blockIdx.y;
  const float* x = side ? xc : xg;
  const u16* W = side ? Wc : Wg;
  float* h  = side ? hc : hg;
  u16*  hT  = side ? hTc : hTg;
  const int r0 = blockIdx.x * 64;
  const int t = threadIdx.x;
  const int wid = t >> 6, lane = t & 63;
  const int lrow = lane & 15, lhi = lane >> 4;

  __shared__ __align__(16) char smem[32768];

  f32x4 acc[4][2];
  const f32x4 z4 = {0.f,0.f,0.f,0.f};
  #pragma unroll
  for(int i=0;i<4;i++){ acc[i][0]=z4; acc[i][1]=z4; }

  const int r = t >> 3, c8 = t & 7;
  for(int k0 = 0; k0 < FIN; k0 += 64){
    const float* xp = x + (size_t)(r0 + r)*FIN + k0 + c8*8;
    float4 xa = *(const float4*)xp;
    float4 xb = *(const float4*)(xp + 4);
    short8 xv;
    xv[0]=(short)f2bf(xa.x); xv[1]=(short)f2bf(xa.y);
    xv[2]=(short)f2bf(xa.z); xv[3]=(short)f2bf(xa.w);
    xv[4]=(short)f2bf(xb.x); xv[5]=(short)f2bf(xb.y);
    xv[6]=(short)f2bf(xb.z); xv[7]=(short)f2bf(xb.w);
    int wbyte = r*128 + (((c8 ^ (r & 7)) & 7) << 4);
    *(short8*)(smem + wbyte) = xv;
    __syncthreads();
    #pragma unroll
    for(int ksub = 0; ksub < 2; ksub++){
      short8 b[2];
      #pragma unroll
      for(int nf=0; nf<2; nf++){
        int n = wid*32 + nf*16 + lrow;
        b[nf] = *(const short8*)(W + (size_t)n*FIN + k0 + ksub*32 + lhi*8);
      }
      #pragma unroll
      for(int mf=0; mf<4; mf++){
        int row = mf*16 + lrow;
        int g = ksub*4 + lhi;
        short8 a = *(const short8*)(smem + row*128 + (((g ^ (row & 7)) & 7) << 4));
        #pragma unroll
        for(int nf=0; nf<2; nf++)
          acc[mf][nf] = __builtin_amdgcn_mfma_f32_16x16x32_bf16(a, b[nf], acc[mf][nf], 0,0,0);
      }
    }
    __syncthreads();
  }
  // write h (f32) and stage bf16 transpose in LDS
  #pragma unroll
  for(int mf=0; mf<4; mf++){
    #pragma unroll
    for(int nf=0; nf<2; nf++){
      int col = wid*32 + nf*16 + lrow;
      #pragma unroll
      for(int j=0;j<4;j++){
        int row = mf*16 + lhi*4 + j;
        float v = acc[mf][nf][j];
        h[(size_t)(r0+row)*DD + col] = v;
        int byte_ = col*128 + (((row*2) ^ ((col & 7)<<4)));
        *(u16*)(smem + byte_) = f2bf(v);
      }
    }
  }
  __syncthreads();
  { // coalesced hT store: thread -> (n = t>>1, half = t&1)
    int n = t >> 1, half = t & 1;
    #pragma unroll
    for(int gi=0; gi<4; gi++){
      int g = half*4 + gi;
      int byte_ = n*128 + (((g ^ (n & 7)) & 7) << 4);
      short8 v = *(const short8*)(smem + byte_);
      *(short8*)(hT + (size_t)n*NGC + r0 + g*8) = v;
    }
  }
}

// ---------------------------------------------------------------------------
// k_svec: per-row dot products with attention vectors + gate sigmoid.
// sbuf layout (each 4096 f32):
// 0 s1gg 1 s2gg 2 s1gc 3 s2cg 4 gam_g 5 s1cc 6 s2cc 7 s2gc 8 s1cg 9 gam_c
// ---------------------------------------------------------------------------
__global__ __launch_bounds__(256) void k_svec(
    const float* __restrict__ hg, const float* __restrict__ hc,
    const float* __restrict__ a_gg, const float* __restrict__ a_gc,
    const float* __restrict__ a_cc, const float* __restrict__ a_cg,
    const float* __restrict__ gw_g, const float* __restrict__ gb_g,
    const float* __restrict__ gw_c, const float* __restrict__ gb_c,
    float* __restrict__ sbuf)
{
  int t = threadIdx.x, wid = t>>6, lane = t&63;
  int idx = blockIdx.x * 4 + wid;          // 0..8191
  int side = idx >> 12;
  int row  = idx & 4095;
  const float* h = (side ? hc : hg) + (size_t)row*DD;
  const float* v0 = (side ? a_cc : a_gg);        // same-type s1 half
  const float* v1 = (side ? a_cc : a_gg) + DD;   // same-type s2 half
  const float* v2 = (side ? a_cg : a_gc);        // cross s1 (this node as src)
  const float* v3 = (side ? a_gc : a_cg) + DD;   // cross s2 (this node as dst)
  const float* gw = side ? gw_c : gw_g;
  float bias = (side ? gb_c : gb_g)[0];

  float4 hv = *(const float4*)(h + lane*4);
  float4 w0 = *(const float4*)(v0 + lane*4);
  float4 w1 = *(const float4*)(v1 + lane*4);
  float4 w2 = *(const float4*)(v2 + lane*4);
  float4 w3 = *(const float4*)(v3 + lane*4);
  float4 w4 = *(const float4*)(gw + lane*4);

  float d0 = hv.x*w0.x + hv.y*w0.y + hv.z*w0.z + hv.w*w0.w;
  float d1 = hv.x*w1.x + hv.y*w1.y + hv.z*w1.z + hv.w*w1.w;
  float d2 = hv.x*w2.x + hv.y*w2.y + hv.z*w2.z + hv.w*w2.w;
  float d3 = hv.x*w3.x + hv.y*w3.y + hv.z*w3.z + hv.w*w3.w;
  float d4 = hv.x*w4.x + hv.y*w4.y + hv.z*w4.z + hv.w*w4.w;
  #pragma unroll
  for(int s=1;s<64;s<<=1){
    d0 += __shfl_xor(d0, s); d1 += __shfl_xor(d1, s); d2 += __shfl_xor(d2, s);
    d3 += __shfl_xor(d3, s); d4 += __shfl_xor(d4, s);
  }
  if(lane == 0){
    float gam = 1.f/(1.f + __expf(-(d4 + bias)));
    if(side == 0){
      sbuf[0*4096+row]=d0; sbuf[1*4096+row]=d1; sbuf[2*4096+row]=d2;
      sbuf[3*4096+row]=d3; sbuf[4*4096+row]=gam;
    } else {
      sbuf[5*4096+row]=d0; sbuf[6*4096+row]=d1; sbuf[8*4096+row]=d2;
      sbuf[7*4096+row]=d3; sbuf[9*4096+row]=gam;
    }
  }
}

// ---------------------------------------------------------------------------
// k_max: global max of the 4 "s2" arrays (one wave each). grid 1 x 256thr.
// ---------------------------------------------------------------------------
__global__ __launch_bounds__(256) void k_max(const float* __restrict__ sbuf,
                                             float* __restrict__ mx)
{
  int t = threadIdx.x, wid = t>>6, lane = t&63;
  const int offs[4] = {1,7,6,3};  // s2gg, s2gc(cell), s2cc, s2cg(gene)
  const float* a = sbuf + offs[wid]*4096;
  float m = -1e30f;
  for(int i = lane; i < 4096; i += 64) m = fmaxf(m, a[i]);
  #pragma unroll
  for(int s=1;s<64;s<<=1) m = fmaxf(m, __shfl_xor(m, s));
  if(lane==0) mx[wid] = m;
}

// ---------------------------------------------------------------------------
// k_gat: masked-softmax attention. grid (128 row-tiles, 4 modes), 256 thr.
// 32 rows x 256 cols per block (4 waves x 64 cols) -> 512 blocks = 2/CU.
// Double-buffered P tile, ONE barrier per k-step; B-frags prefetched 1 step
// ahead, s2/mask 2 steps ahead. Mask bits PLAIN layout (L2-resident).
// m_i = leaky(s1_i + max_j s2_j) bounds all logits -> no online rescale.
// ---------------------------------------------------------------------------
__global__ __launch_bounds__(256,2) void k_gat(
    const float* __restrict__ sbuf, const float* __restrict__ mx,
    const uint8_t* __restrict__ packbits, const uint8_t* __restrict__ bitsT,
    const u16* __restrict__ hTg, const u16* __restrict__ hTc,
    float* __restrict__ blk)
{
  const int mode = blockIdx.y;
  const float* s1; const float* s2; const uint8_t* bits;
  const u16* vT; float* outp;
  if(mode == 0){ s1 = sbuf+0*4096; s2 = sbuf+1*4096; bits = packbits;           vT = hTg; outp = blk; }
  else if(mode == 1){ s1 = sbuf+2*4096; s2 = sbuf+7*4096; bits = packbits + 4194304; vT = hTc; outp = blk + 1048576; }
  else if(mode == 2){ s1 = sbuf+5*4096; s2 = sbuf+6*4096; bits = packbits + 2097152; vT = hTc; outp = blk + 2097152; }
  else { s1 = sbuf+8*4096; s2 = sbuf+3*4096; bits = bitsT; vT = hTg; outp = blk + 3145728; }

  const float maxs2 = mx[mode];
  const int r0 = blockIdx.x * 32;
  const int t = threadIdx.x;
  const int wid = t>>6, lane = t&63, lrow = lane&15, lhi = lane>>4;
  const int r = t>>3, c8 = t&7;
  const int srow = r0 + r;
  const int n0 = wid*64;

  __shared__ __align__(16) char psmem[8192];   // 2 x (32x64 bf16) double buffer
  __shared__ float zbuf[32];

  const float s1v = s1[srow];
  const float m = lk(s1v + maxs2);
  float zacc = 0.f;
  const f32x4 z4 = {0.f,0.f,0.f,0.f};
  f32x4 acc[2][4];
  #pragma unroll
  for(int i=0;i<2;i++){ acc[i][0]=z4; acc[i][1]=z4; acc[i][2]=z4; acc[i][3]=z4; }

  const uint8_t* brow = bits + (size_t)srow*512 + c8;  // step ks byte at + ks*8
  const float* s2base = s2 + c8*8;
  const int pwbyte = r*128 + (((c8 ^ (r&7)) & 7) << 4);

  float4 s2A[2], s2B[2]; u32 mb[2];
  short8 B[2][8];

  // ---- prologue: loads for steps 0 & 1, B for step 0; p-gen step 0 ----
  s2A[0] = *(const float4*)(s2base);
  s2B[0] = *(const float4*)(s2base + 4);
  mb[0]  = brow[0];
  s2A[1] = *(const float4*)(s2base + 64);
  s2B[1] = *(const float4*)(s2base + 68);
  mb[1]  = brow[8];
  #pragma unroll
  for(int ksub=0;ksub<2;ksub++)
    #pragma unroll
    for(int nf=0;nf<4;nf++)
      B[0][ksub*4+nf] = *(const short8*)(vT + (size_t)(n0+nf*16+lrow)*NGC + ksub*32 + lhi*8);
  {
    float s2v[8] = {s2A[0].x,s2A[0].y,s2A[0].z,s2A[0].w,s2B[0].x,s2B[0].y,s2B[0].z,s2B[0].w};
    short8 pw;
    #pragma unroll
    for(int j=0;j<8;j++){
      float e = __expf(lk(s1v + s2v[j]) - m);
      float p = ((mb[0]>>j)&1u) ? e : 0.0f;
      zacc += p; pw[j] = (short)f2bf(p);
    }
    *(short8*)(psmem + pwbyte) = pw;
  }
  __syncthreads();

  // ---- main loop: one barrier per step ----
  #pragma unroll 2
  for(int ks = 0; ks < 64; ks++){
    const int par = ks & 1, parn = par ^ 1;
    const int k0 = ks*64;
    // issue B loads for step ks+1
    if(ks < 63){
      #pragma unroll
      for(int ksub=0;ksub<2;ksub++)
        #pragma unroll
        for(int nf=0;nf<4;nf++)
          B[parn][ksub*4+nf] = *(const short8*)(vT + (size_t)(n0+nf*16+lrow)*NGC + (k0+64) + ksub*32 + lhi*8);
    }
    // issue s2/mask loads for step ks+2
    if(ks < 62){
      s2A[par] = *(const float4*)(s2base + k0 + 128);
      s2B[par] = *(const float4*)(s2base + k0 + 132);
      mb[par]  = brow[(ks+2)*8];
    }
    // p-gen for step ks+1 into buf[parn]
    if(ks < 63){
      float s2v[8] = {s2A[parn].x,s2A[parn].y,s2A[parn].z,s2A[parn].w,
                      s2B[parn].x,s2B[parn].y,s2B[parn].z,s2B[parn].w};
      u32 mm = mb[parn];
      short8 pw;
      #pragma unroll
      for(int j=0;j<8;j++){
        float e = __expf(lk(s1v + s2v[j]) - m);
        float p = ((mm>>j)&1u) ? e : 0.0f;
        zacc += p; pw[j] = (short)f2bf(p);
      }
      *(short8*)(psmem + parn*4096 + pwbyte) = pw;
    }
    // MFMA from buf[par] with B[par]
    #pragma unroll
    for(int ksub=0;ksub<2;ksub++){
      short8 a[2];
      #pragma unroll
      for(int mf=0;mf<2;mf++){
        int row = mf*16 + lrow;
        int g = ksub*4 + lhi;
        a[mf] = *(const short8*)(psmem + par*4096 + row*128 + (((g ^ (row&7)) & 7) << 4));
      }
      #pragma unroll
      for(int mf=0;mf<2;mf++)
        #pragma unroll
        for(int nf=0;nf<4;nf++)
          acc[mf][nf] = __builtin_amdgcn_mfma_f32_16x16x32_bf16(a[mf], B[par][ksub*4+nf], acc[mf][nf], 0,0,0);
    }
    __syncthreads();
  }

  // ---- Z reduction (8 threads per row are adjacent lanes) ----
  float z = zacc;
  z += __shfl_xor(z, 1);
  z += __shfl_xor(z, 2);
  z += __shfl_xor(z, 4);
  if(c8 == 0) zbuf[r] = z;
  __syncthreads();
  // ---- normalize + store ----
  #pragma unroll
  for(int mf=0; mf<2; mf++){
    #pragma unroll
    for(int j=0;j<4;j++){
      int row = mf*16 + lhi*4 + j;
      float rz = 1.f / fmaxf(zbuf[row], 1e-30f);
      #pragma unroll
      for(int nf=0; nf<4; nf++){
        int col = n0 + nf*16 + lrow;
        outp[(size_t)(r0+row)*DD + col] = acc[mf][nf][j] * rz;
      }
    }
  }
}

// ---------------------------------------------------------------------------
// k_epi: out = leaky(h + same + gamma*cross) for both sides.
// ---------------------------------------------------------------------------
__global__ __launch_bounds__(256) void k_epi(
    const float* __restrict__ hg, const float* __restrict__ hc,
    const float* __restrict__ blk, const float* __restrict__ sbuf,
    float* __restrict__ out)
{
  int i = blockIdx.x*256 + threadIdx.x;
  int base = i*4;
  int row = base >> 8;
  float gg = sbuf[4*4096 + row];
  float4 h4 = *(const float4*)(hg + base);
  float4 a4 = *(const float4*)(blk + base);
  float4 b4 = *(const float4*)(blk + 1048576 + base);
  float4 o;
  o.x = lk(h4.x + a4.x + gg*b4.x);
  o.y = lk(h4.y + a4.y + gg*b4.y);
  o.z = lk(h4.z + a4.z + gg*b4.z);
  o.w = lk(h4.w + a4.w + gg*b4.w);
  *(float4*)(out + base) = o;

  float gc = sbuf[9*4096 + row];
  float4 h4c = *(const float4*)(hc + base);
  float4 c4 = *(const float4*)(blk + 2097152 + base);
  float4 d4 = *(const float4*)(blk + 3145728 + base);
  float4 o2;
  o2.x = lk(h4c.x + c4.x + gc*d4.x);
  o2.y = lk(h4c.y + c4.y + gc*d4.y);
  o2.z = lk(h4c.z + c4.z + gc*d4.z);
  o2.w = lk(h4c.w + c4.w + gc*d4.w);
  *(float4*)(out + 1048576 + base) = o2;
}

// ---------------------------------------------------------------------------
extern "C" void kernel_launch(void* const* d_in, const int* in_sizes, int n_in,
                              void* d_out, int out_size, void* d_ws, size_t ws_size,
                              hipStream_t stream)
{
  const float* gene_x   = (const float*)d_in[0];
  const float* cell_x   = (const float*)d_in[1];
  const float* gene_adj = (const float*)d_in[2];
  const float* cell_adj = (const float*)d_in[3];
  const float* gc_adj   = (const float*)d_in[4];
  const float* Wg       = (const float*)d_in[5];
  const float* Wc       = (const float*)d_in[6];
  const float* a_gg     = (const float*)d_in[7];
  const float* a_gc     = (const float*)d_in[8];
  const float* a_cc     = (const float*)d_in[9];
  const float* a_cg     = (const float*)d_in[10];
  const float* gw_g     = (const float*)d_in[11];
  const float* gb_g     = (const float*)d_in[12];
  const float* gw_c     = (const float*)d_in[13];
  const float* gb_c     = (const float*)d_in[14];

  char* ws = (char*)d_ws;
  float* hg   = (float*)(ws);
  float* hc   = (float*)(ws + (4u<<20));
  u16*   hTg  = (u16*)  (ws + (8u<<20));
  u16*   hTc  = (u16*)  (ws + (10u<<20));
  float* sbuf = (float*)(ws + (12u<<20));
  float* mx   = (float*)(ws + (12u<<20) + (256u<<10));
  uint8_t* bitsT = (uint8_t*)(ws + (13u<<20));   // 2MB
  u16*   Wgbf = (u16*)  (ws + (15u<<20));
  u16*   Wcbf = (u16*)  (ws + (15u<<20) + (512u<<10));
  float* blk  = (float*)(ws + (16u<<20));        // 16MB
  u64*   packbits = (u64*)(ws + (32u<<20));      // 6MB: gene@+0, cell@+2MB, gc@+4MB

  k_wcvt<<<dim3(128), 256, 0, stream>>>(Wg, Wc, Wgbf, Wcbf);
  k_pack<<<dim3(3072), 256, 0, stream>>>(gene_adj, cell_adj, gc_adj, packbits);
  k_bitTT<<<dim3(1024), 256, 0, stream>>>(packbits + 524288, (u64*)bitsT);
  k_hgemm<<<dim3(64,2), 512, 0, stream>>>(gene_x, cell_x, Wgbf, Wcbf, hg, hc, hTg, hTc);
  k_svec<<<dim3(2048), 256, 0, stream>>>(hg, hc, a_gg, a_gc, a_cc, a_cg,
                                         gw_g, gb_g, gw_c, gb_c, sbuf);
  k_max<<<dim3(1), 256, 0, stream>>>(sbuf, mx);
  k_gat<<<dim3(128,4), 256, 0, stream>>>(sbuf, mx, (const uint8_t*)packbits,
                                         bitsT, hTg, hTc, blk);
  k_epi<<<dim3(1024), 256, 0, stream>>>(hg, hc, blk, sbuf, (float*)d_out);
}

// Round 6
// 189.006 us; speedup vs baseline: 1.1631x; 1.1631x over previous
//
#include <hip/hip_runtime.h>
#include <stdint.h>

#define NGC 4096   // both node counts
#define FIN 512
#define DD  256

typedef __attribute__((ext_vector_type(8))) short short8;
typedef __attribute__((ext_vector_type(4))) float f32x4;
typedef unsigned short u16;
typedef unsigned int   u32;
typedef unsigned long long u64;

static __device__ __forceinline__ float bf2f(u16 u){ return __uint_as_float(((u32)u)<<16); }
static __device__ __forceinline__ u16 f2bf(float f){
  u32 u = __float_as_uint(f);
  u += 0x7fffu + ((u>>16)&1u);
  return (u16)(u>>16);
}
static __device__ __forceinline__ float lk(float x){ return fmaxf(x, 0.2f*x); }
static __device__ __forceinline__ u64 shfl_xor64(u64 x, int m){
  u32 lo = (u32)x, hi = (u32)(x >> 32);
  lo = __shfl_xor(lo, m); hi = __shfl_xor(hi, m);
  return ((u64)hi << 32) | lo;
}

// ---------------------------------------------------------------------------
// k_wcvt: W (f32) -> bf16 copies for the GEMM.
// ---------------------------------------------------------------------------
__global__ __launch_bounds__(256) void k_wcvt(
    const float* __restrict__ Wg, const float* __restrict__ Wc,
    u16* __restrict__ Wgbf, u16* __restrict__ Wcbf)
{
  int base = (blockIdx.x*256 + threadIdx.x)*4;   // grid 128 -> 131072 elems
  float4 a = *(const float4*)(Wg + base);
  float4 b = *(const float4*)(Wc + base);
  ushort4 oa, ob;
  oa.x=f2bf(a.x); oa.y=f2bf(a.y); oa.z=f2bf(a.z); oa.w=f2bf(a.w);
  ob.x=f2bf(b.x); ob.y=f2bf(b.y); ob.z=f2bf(b.z); ob.w=f2bf(b.w);
  *(ushort4*)(Wgbf + base) = oa;
  *(ushort4*)(Wcbf + base) = ob;
}

// ---------------------------------------------------------------------------
// k_pack: bit-pack 3 adjacency matrices (f32 0/1 -> 1 bit), PLAIN layout:
// bit k of row r at u64 word [r*64 + k/64]. One wave per row; float4 loads
// + shuffle-tree compaction -> one u64 per lane -> coalesced 512B store.
// ---------------------------------------------------------------------------
__global__ __launch_bounds__(256) void k_pack(
    const float* __restrict__ gene_adj, const float* __restrict__ cell_adj,
    const float* __restrict__ gc_adj,   u64* __restrict__ packbits)
{
  int t = threadIdx.x, wid = t>>6, lane = t&63;
  int gw = blockIdx.x*4 + wid;          // 0..12287
  int mat = gw >> 12;
  int row = gw & 4095;
  const float* src = (mat==0) ? gene_adj : (mat==1) ? cell_adj : gc_adj;
  const float* rp = src + (size_t)row*NGC;

  u64 myword = 0;
  #pragma unroll
  for(int i = 0; i < 16; i++){
    float4 v = *(const float4*)(rp + i*256 + lane*4);
    u32 nib = (v.x!=0.f?1u:0u) | (v.y!=0.f?2u:0u) | (v.z!=0.f?4u:0u) | (v.w!=0.f?8u:0u);
    u32 b  = nib | (__shfl_xor((int)nib, 1) << 4);   // even lanes: byte
    u32 h  = b   | (__shfl_xor((int)b,   2) << 8);   // lanes%4==0: u16
    u32 w  = h   | (__shfl_xor((int)h,   4) << 16);  // lanes%8==0: u32
    u32 o  = (u32)__shfl_xor((int)w, 8);             // lanes%16==0: pair
    u32 flo = w, fhi = o;                            // u64 at lanes 16q: elems [i*256+64q, +64)
    int srcl = ((lane - i*4) << 4) & 63;             // target lanes i*4+q read from lane 16q
    u32 glo = (u32)__shfl((int)flo, srcl);
    u32 ghi = (u32)__shfl((int)fhi, srcl);
    if((lane >> 2) == i) myword = ((u64)ghi << 32) | (u64)glo;
  }
  packbits[((size_t)mat << 18) + (size_t)row*64 + lane] = myword;
}

// ---------------------------------------------------------------------------
// k_bitTT: transpose gc bits -> bitsT (both PLAIN layout, u64 load/store).
// One wave per 64x64-bit tile; 4096 tiles; 4 waves/block -> 1024 blocks.
// ---------------------------------------------------------------------------
__global__ __launch_bounds__(256) void k_bitTT(
    const u64* __restrict__ gcb, u64* __restrict__ bT)
{
  int t = threadIdx.x, wid = t>>6, lane = t&63;
  int id = blockIdx.x*4 + wid;          // 0..4095
  int G = id & 63, C = id >> 6;

  u64 x = gcb[(size_t)(64*G + lane)*64 + C];

  const u64 M1  = 0xAAAAAAAAAAAAAAAAull;
  const u64 M2  = 0xCCCCCCCCCCCCCCCCull;
  const u64 M4  = 0xF0F0F0F0F0F0F0F0ull;
  const u64 M8  = 0xFF00FF00FF00FF00ull;
  const u64 M16 = 0xFFFF0000FFFF0000ull;
  const u64 M32 = 0xFFFFFFFF00000000ull;
  #define TSTEP(S, M) { u64 y = shfl_xor64(x, S); \
    x = (lane & S) ? ((x & (M)) | ((y >> S) & ~(M))) \
                   : ((x & ~(M)) | ((y << S) & (M))); }
  TSTEP(32, M32) TSTEP(16, M16) TSTEP(8, M8)
  TSTEP(4,  M4)  TSTEP(2,  M2)  TSTEP(1, M1)
  #undef TSTEP

  bT[(size_t)(64*C + lane)*64 + G] = x;
}

// ---------------------------------------------------------------------------
// k_hgemm: h = x @ W.T  (f32 x in -> bf16 staged, f32 h out + bf16 hT out)
// grid (64 row-tiles, 2 sides), 512 threads (8 waves). BM=64, BK=64, N=256.
// ---------------------------------------------------------------------------
__global__ __launch_bounds__(512) void k_hgemm(
    const float* __restrict__ xg, const float* __restrict__ xc,
    const u16* __restrict__ Wg, const u16* __restrict__ Wc,
    float* __restrict__ hg, float* __restrict__ hc,
    u16* __restrict__ hTg, u16* __restrict__ hTc)
{
  const int side = blockIdx.y;
  const float* x = side ? xc : xg;
  const u16* W = side ? Wc : Wg;
  float* h  = side ? hc : hg;
  u16*  hT  = side ? hTc : hTg;
  const int r0 = blockIdx.x * 64;
  const int t = threadIdx.x;
  const int wid = t >> 6, lane = t & 63;
  const int lrow = lane & 15, lhi = lane >> 4;

  __shared__ __align__(16) char smem[32768];

  f32x4 acc[4][2];
  const f32x4 z4 = {0.f,0.f,0.f,0.f};
  #pragma unroll
  for(int i=0;i<4;i++){ acc[i][0]=z4; acc[i][1]=z4; }

  const int r = t >> 3, c8 = t & 7;
  for(int k0 = 0; k0 < FIN; k0 += 64){
    const float* xp = x + (size_t)(r0 + r)*FIN + k0 + c8*8;
    float4 xa = *(const float4*)xp;
    float4 xb = *(const float4*)(xp + 4);
    short8 xv;
    xv[0]=(short)f2bf(xa.x); xv[1]=(short)f2bf(xa.y);
    xv[2]=(short)f2bf(xa.z); xv[3]=(short)f2bf(xa.w);
    xv[4]=(short)f2bf(xb.x); xv[5]=(short)f2bf(xb.y);
    xv[6]=(short)f2bf(xb.z); xv[7]=(short)f2bf(xb.w);
    int wbyte = r*128 + (((c8 ^ (r & 7)) & 7) << 4);
    *(short8*)(smem + wbyte) = xv;
    __syncthreads();
    #pragma unroll
    for(int ksub = 0; ksub < 2; ksub++){
      short8 b[2];
      #pragma unroll
      for(int nf=0; nf<2; nf++){
        int n = wid*32 + nf*16 + lrow;
        b[nf] = *(const short8*)(W + (size_t)n*FIN + k0 + ksub*32 + lhi*8);
      }
      #pragma unroll
      for(int mf=0; mf<4; mf++){
        int row = mf*16 + lrow;
        int g = ksub*4 + lhi;
        short8 a = *(const short8*)(smem + row*128 + (((g ^ (row & 7)) & 7) << 4));
        #pragma unroll
        for(int nf=0; nf<2; nf++)
          acc[mf][nf] = __builtin_amdgcn_mfma_f32_16x16x32_bf16(a, b[nf], acc[mf][nf], 0,0,0);
      }
    }
    __syncthreads();
  }
  // write h (f32) and stage bf16 transpose in LDS
  #pragma unroll
  for(int mf=0; mf<4; mf++){
    #pragma unroll
    for(int nf=0; nf<2; nf++){
      int col = wid*32 + nf*16 + lrow;
      #pragma unroll
      for(int j=0;j<4;j++){
        int row = mf*16 + lhi*4 + j;
        float v = acc[mf][nf][j];
        h[(size_t)(r0+row)*DD + col] = v;
        int byte_ = col*128 + (((row*2) ^ ((col & 7)<<4)));
        *(u16*)(smem + byte_) = f2bf(v);
      }
    }
  }
  __syncthreads();
  { // coalesced hT store: thread -> (n = t>>1, half = t&1)
    int n = t >> 1, half = t & 1;
    #pragma unroll
    for(int gi=0; gi<4; gi++){
      int g = half*4 + gi;
      int byte_ = n*128 + (((g ^ (n & 7)) & 7) << 4);
      short8 v = *(const short8*)(smem + byte_);
      *(short8*)(hT + (size_t)n*NGC + r0 + g*8) = v;
    }
  }
}

// ---------------------------------------------------------------------------
// k_svec: per-row dot products with attention vectors + gate sigmoid.
// sbuf layout (each 4096 f32):
// 0 s1gg 1 s2gg 2 s1gc 3 s2cg 4 gam_g 5 s1cc 6 s2cc 7 s2gc 8 s1cg 9 gam_c
// ---------------------------------------------------------------------------
__global__ __launch_bounds__(256) void k_svec(
    const float* __restrict__ hg, const float* __restrict__ hc,
    const float* __restrict__ a_gg, const float* __restrict__ a_gc,
    const float* __restrict__ a_cc, const float* __restrict__ a_cg,
    const float* __restrict__ gw_g, const float* __restrict__ gb_g,
    const float* __restrict__ gw_c, const float* __restrict__ gb_c,
    float* __restrict__ sbuf)
{
  int t = threadIdx.x, wid = t>>6, lane = t&63;
  int idx = blockIdx.x * 4 + wid;          // 0..8191
  int side = idx >> 12;
  int row  = idx & 4095;
  const float* h = (side ? hc : hg) + (size_t)row*DD;
  const float* v0 = (side ? a_cc : a_gg);        // same-type s1 half
  const float* v1 = (side ? a_cc : a_gg) + DD;   // same-type s2 half
  const float* v2 = (side ? a_cg : a_gc);        // cross s1 (this node as src)
  const float* v3 = (side ? a_gc : a_cg) + DD;   // cross s2 (this node as dst)
  const float* gw = side ? gw_c : gw_g;
  float bias = (side ? gb_c : gb_g)[0];

  float4 hv = *(const float4*)(h + lane*4);
  float4 w0 = *(const float4*)(v0 + lane*4);
  float4 w1 = *(const float4*)(v1 + lane*4);
  float4 w2 = *(const float4*)(v2 + lane*4);
  float4 w3 = *(const float4*)(v3 + lane*4);
  float4 w4 = *(const float4*)(gw + lane*4);

  float d0 = hv.x*w0.x + hv.y*w0.y + hv.z*w0.z + hv.w*w0.w;
  float d1 = hv.x*w1.x + hv.y*w1.y + hv.z*w1.z + hv.w*w1.w;
  float d2 = hv.x*w2.x + hv.y*w2.y + hv.z*w2.z + hv.w*w2.w;
  float d3 = hv.x*w3.x + hv.y*w3.y + hv.z*w3.z + hv.w*w3.w;
  float d4 = hv.x*w4.x + hv.y*w4.y + hv.z*w4.z + hv.w*w4.w;
  #pragma unroll
  for(int s=1;s<64;s<<=1){
    d0 += __shfl_xor(d0, s); d1 += __shfl_xor(d1, s); d2 += __shfl_xor(d2, s);
    d3 += __shfl_xor(d3, s); d4 += __shfl_xor(d4, s);
  }
  if(lane == 0){
    float gam = 1.f/(1.f + __expf(-(d4 + bias)));
    if(side == 0){
      sbuf[0*4096+row]=d0; sbuf[1*4096+row]=d1; sbuf[2*4096+row]=d2;
      sbuf[3*4096+row]=d3; sbuf[4*4096+row]=gam;
    } else {
      sbuf[5*4096+row]=d0; sbuf[6*4096+row]=d1; sbuf[8*4096+row]=d2;
      sbuf[7*4096+row]=d3; sbuf[9*4096+row]=gam;
    }
  }
}

// ---------------------------------------------------------------------------
// k_gat: O^T = V^T * P^T with P generated in-register as the MFMA B-operand.
// grid (64 rowgroups, 2 kchunks, 4 modes) = 512 blocks, 256 thr (4 waves).
// Block: 64 src rows x 256 d, each wave one 64-d group; kchunk = 2048.
// NO barriers in the 64-step main loop. Split-K partials are additive since
// the softmax stabilizer m = lk(s1_i + max_j s2_j) is a global per-mode bound
// (computed identically in every block). Partials reduced in k_epi.
// ---------------------------------------------------------------------------
__global__ __launch_bounds__(256,2) void k_gat(
    const float* __restrict__ sbuf,
    const uint8_t* __restrict__ packbits, const uint8_t* __restrict__ bitsT,
    const u16* __restrict__ hTg, const u16* __restrict__ hTc,
    float* __restrict__ part, float* __restrict__ Zpart)
{
  const int mode = blockIdx.z;
  const int kc   = blockIdx.y;
  const int rowbase = blockIdx.x * 64;
  const int kcbase  = kc * 2048;

  const float* s1; const float* s2; const uint8_t* bits; const u16* hT;
  if(mode == 0){ s1 = sbuf;        s2 = sbuf+4096;   bits = packbits;           hT = hTg; }
  else if(mode == 1){ s1 = sbuf+2*4096; s2 = sbuf+7*4096; bits = packbits+4194304; hT = hTc; }
  else if(mode == 2){ s1 = sbuf+5*4096; s2 = sbuf+6*4096; bits = packbits+2097152; hT = hTc; }
  else { s1 = sbuf+8*4096; s2 = sbuf+3*4096; bits = bitsT; hT = hTg; }

  const int t = threadIdx.x, wid = t>>6, lane = t&63, lrow = lane&15, lhi = lane>>4;
  const int dbase = wid*64;

  __shared__ __align__(16) char U[66560];   // mask[64][272] + s2[2048] ; reused as T[64][260]
  __shared__ float red[4];
  char*  mask_l = U;
  float* s2_l   = (float*)(U + 17408);

  // ---- stage mask chunk (16KB, coalesced 16B copies) ----
  {
    int row = t>>2, seg = t&3;
    const char* g = (const char*)bits + (size_t)(rowbase+row)*512 + (kcbase>>3) + seg*64;
    char* d = mask_l + row*272 + seg*64;
    #pragma unroll
    for(int i=0;i<4;i++)
      *(ulonglong2*)(d + i*16) = *(const ulonglong2*)(g + i*16);
  }
  // ---- stage s2 chunk (8KB) ----
  {
    const float* g = s2 + kcbase + t*8;
    *(float4*)(s2_l + t*8)     = *(const float4*)(g);
    *(float4*)(s2_l + t*8 + 4) = *(const float4*)(g + 4);
  }
  // ---- block-local max over FULL s2 (deterministic, identical per mode) ----
  float mxv = -1e30f;
  #pragma unroll
  for(int i=0;i<4;i++){
    float4 v = *(const float4*)(s2 + t*16 + i*4);
    mxv = fmaxf(mxv, fmaxf(fmaxf(v.x,v.y), fmaxf(v.z,v.w)));
  }
  #pragma unroll
  for(int sh=1; sh<64; sh<<=1) mxv = fmaxf(mxv, __shfl_xor(mxv, sh));
  if(lane==0) red[wid] = mxv;
  __syncthreads();
  const float maxs2 = fmaxf(fmaxf(red[0],red[1]), fmaxf(red[2],red[3]));

  // per-nf row constants
  float c1[4], c2[4], z[4];
  #pragma unroll
  for(int nf=0; nf<4; nf++){
    float s1v = s1[rowbase + nf*16 + lrow];
    float m = lk(s1v + maxs2);
    c1[nf] = s1v - m;
    c2[nf] = 0.2f*s1v - m;
    z[nf] = 0.f;
  }

  f32x4 acc[4][4];
  const f32x4 zz = {0.f,0.f,0.f,0.f};
  #pragma unroll
  for(int i=0;i<4;i++){ acc[i][0]=zz; acc[i][1]=zz; acc[i][2]=zz; acc[i][3]=zz; }

  const u16* pA = hT + (size_t)(dbase + lrow)*4096 + kcbase + lhi*8;
  const float* ps2 = s2_l + lhi*8;
  const u32* pM0 = (const u32*)(mask_l + (lrow   )*272);
  const u32* pM1 = (const u32*)(mask_l + (16+lrow)*272);
  const u32* pM2 = (const u32*)(mask_l + (32+lrow)*272);
  const u32* pM3 = (const u32*)(mask_l + (48+lrow)*272);

  // ---- main loop: zero barriers ----
  for(int s=0; s<64; s++){
    const int kl = s*32;
    short8 av[4];
    av[0] = *(const short8*)(pA + kl);
    av[1] = *(const short8*)(pA + 16*4096 + kl);
    av[2] = *(const short8*)(pA + 32*4096 + kl);
    av[3] = *(const short8*)(pA + 48*4096 + kl);
    float4 sA = *(const float4*)(ps2 + kl);
    float4 sB = *(const float4*)(ps2 + kl + 4);
    float s2v[8] = {sA.x,sA.y,sA.z,sA.w,sB.x,sB.y,sB.z,sB.w};
    u32 mword[4] = {pM0[s], pM1[s], pM2[s], pM3[s]};
    short8 b[4];
    #pragma unroll
    for(int nf=0; nf<4; nf++){
      u32 mw = mword[nf];
      u32 w[4];
      #pragma unroll
      for(int pr=0; pr<4; pr++){
        float sv0 = s2v[2*pr],   sv1 = s2v[2*pr+1];
        float bit0 = (float)((mw >> (lhi*8 + 2*pr  )) & 1u);
        float bit1 = (float)((mw >> (lhi*8 + 2*pr+1)) & 1u);
        float p0 = __expf(fmaxf(c1[nf]+sv0, fmaf(0.2f, sv0, c2[nf]))) * bit0;
        float p1 = __expf(fmaxf(c1[nf]+sv1, fmaf(0.2f, sv1, c2[nf]))) * bit1;
        z[nf] += p0 + p1;
        u32 q0 = __float_as_uint(p0) + 0x8000u;
        u32 q1 = __float_as_uint(p1) + 0x8000u;
        w[pr] = (q1 & 0xFFFF0000u) | (q0 >> 16);
      }
      union { u32 w4[4]; short8 s8; } cvt;
      cvt.w4[0]=w[0]; cvt.w4[1]=w[1]; cvt.w4[2]=w[2]; cvt.w4[3]=w[3];
      b[nf] = cvt.s8;
    }
    #pragma unroll
    for(int mf=0; mf<4; mf++)
      #pragma unroll
      for(int nf=0; nf<4; nf++)
        acc[mf][nf] = __builtin_amdgcn_mfma_f32_16x16x32_bf16(av[mf], b[nf], acc[mf][nf], 0,0,0);
  }

  // ---- Z partials (identical across the 4 dgroup waves; wave 0 writes) ----
  #pragma unroll
  for(int nf=0; nf<4; nf++){
    z[nf] += __shfl_xor(z[nf], 16);
    z[nf] += __shfl_xor(z[nf], 32);
  }
  if(wid == 0 && lane < 16){
    float* zp = Zpart + (size_t)(mode*2 + kc)*4096 + rowbase + lane;
    zp[0]  = z[0]; zp[16] = z[1]; zp[32] = z[2]; zp[48] = z[3];
  }

  // ---- transpose O^T tile -> row-major partial via LDS ----
  __syncthreads();
  float* T = (float*)U;   // [64 nodes][260 f32]
  #pragma unroll
  for(int mf=0; mf<4; mf++)
    #pragma unroll
    for(int nf=0; nf<4; nf++)
      *(f32x4*)(T + (nf*16+lrow)*260 + dbase + mf*16 + lhi*4) = acc[mf][nf];
  __syncthreads();
  float* po = part + ((size_t)(mode*2 + kc) << 20) + (size_t)rowbase*256;
  #pragma unroll
  for(int i=0;i<16;i++){
    int node = i*4 + wid;
    f32x4 v = *(const f32x4*)(T + node*260 + (t&63)*4);
    *(f32x4*)(po + (size_t)node*256 + (t&63)*4) = v;
  }
}

// ---------------------------------------------------------------------------
// k_epi: out = leaky(h + (A0+A1)/za + gamma*(B0+B1)/zb), fused kc-reduce.
// ---------------------------------------------------------------------------
__global__ __launch_bounds__(256) void k_epi(
    const float* __restrict__ hg, const float* __restrict__ hc,
    const float* __restrict__ part, const float* __restrict__ Zpart,
    const float* __restrict__ sbuf, float* __restrict__ out)
{
  int idx = blockIdx.x*256 + threadIdx.x;   // 0..524287
  int fid = idx*4;
  int side = fid >> 20;
  int l = fid & 1048575;
  int node = l >> 8;
  int modeA = side ? 2 : 0, modeB = side ? 3 : 1;
  const float* h = side ? hc : hg;
  float gam = sbuf[(side ? 9 : 4)*4096 + node];
  float za = Zpart[(size_t)(modeA*2)*4096 + node] + Zpart[(size_t)(modeA*2+1)*4096 + node];
  float zb = Zpart[(size_t)(modeB*2)*4096 + node] + Zpart[(size_t)(modeB*2+1)*4096 + node];
  float rza = 1.f / fmaxf(za, 1e-30f);
  float rzb = 1.f / fmaxf(zb, 1e-30f);
  float4 a0 = *(const float4*)(part + ((size_t)(modeA*2  )<<20) + l);
  float4 a1 = *(const float4*)(part + ((size_t)(modeA*2+1)<<20) + l);
  float4 b0 = *(const float4*)(part + ((size_t)(modeB*2  )<<20) + l);
  float4 b1 = *(const float4*)(part + ((size_t)(modeB*2+1)<<20) + l);
  float4 h4 = *(const float4*)(h + l);
  float4 o;
  o.x = lk(h4.x + (a0.x+a1.x)*rza + gam*(b0.x+b1.x)*rzb);
  o.y = lk(h4.y + (a0.y+a1.y)*rza + gam*(b0.y+b1.y)*rzb);
  o.z = lk(h4.z + (a0.z+a1.z)*rza + gam*(b0.z+b1.z)*rzb);
  o.w = lk(h4.w + (a0.w+a1.w)*rza + gam*(b0.w+b1.w)*rzb);
  *(float4*)(out + fid) = o;
}

// ---------------------------------------------------------------------------
extern "C" void kernel_launch(void* const* d_in, const int* in_sizes, int n_in,
                              void* d_out, int out_size, void* d_ws, size_t ws_size,
                              hipStream_t stream)
{
  const float* gene_x   = (const float*)d_in[0];
  const float* cell_x   = (const float*)d_in[1];
  const float* gene_adj = (const float*)d_in[2];
  const float* cell_adj = (const float*)d_in[3];
  const float* gc_adj   = (const float*)d_in[4];
  const float* Wg       = (const float*)d_in[5];
  const float* Wc       = (const float*)d_in[6];
  const float* a_gg     = (const float*)d_in[7];
  const float* a_gc     = (const float*)d_in[8];
  const float* a_cc     = (const float*)d_in[9];
  const float* a_cg     = (const float*)d_in[10];
  const float* gw_g     = (const float*)d_in[11];
  const float* gb_g     = (const float*)d_in[12];
  const float* gw_c     = (const float*)d_in[13];
  const float* gb_c     = (const float*)d_in[14];

  char* ws = (char*)d_ws;
  float* hg   = (float*)(ws);                    // 4MB
  float* hc   = (float*)(ws + (4u<<20));         // 4MB
  u16*   hTg  = (u16*)  (ws + (8u<<20));         // 2MB
  u16*   hTc  = (u16*)  (ws + (10u<<20));        // 2MB
  float* sbuf = (float*)(ws + (12u<<20));        // 160KB
  uint8_t* bitsT = (uint8_t*)(ws + (13u<<20));   // 2MB
  u16*   Wgbf = (u16*)  (ws + (15u<<20));        // 0.5MB
  u16*   Wcbf = (u16*)  (ws + (15u<<20) + (512u<<10));
  float* part = (float*)(ws + (16u<<20));        // 32MB: [mode][kc][node][d]
  float* Zpart= (float*)(ws + (48u<<20));        // 128KB
  u64*   packbits = (u64*)(ws + (49u<<20));      // 6MB: gene, cell, gc

  k_wcvt<<<dim3(128), 256, 0, stream>>>(Wg, Wc, Wgbf, Wcbf);
  k_pack<<<dim3(3072), 256, 0, stream>>>(gene_adj, cell_adj, gc_adj, packbits);
  k_bitTT<<<dim3(1024), 256, 0, stream>>>(packbits + 524288, (u64*)bitsT);
  k_hgemm<<<dim3(64,2), 512, 0, stream>>>(gene_x, cell_x, Wgbf, Wcbf, hg, hc, hTg, hTc);
  k_svec<<<dim3(2048), 256, 0, stream>>>(hg, hc, a_gg, a_gc, a_cc, a_cg,
                                         gw_g, gb_g, gw_c, gb_c, sbuf);
  k_gat<<<dim3(64,2,4), 256, 0, stream>>>(sbuf, (const uint8_t*)packbits,
                                          bitsT, hTg, hTc, part, Zpart);
  k_epi<<<dim3(2048), 256, 0, stream>>>(hg, hc, part, Zpart, sbuf, (float*)d_out);
}